// Round 10
// baseline (541915.625 us; speedup 1.0000x reference)
//
#include <hip/hip_runtime.h>
#include <hip/hip_fp16.h>
#include <stdint.h>

typedef unsigned short ushort_t;
typedef unsigned int uint_t;
typedef unsigned long long ull_t;

#define TSTEPS 512
#define BATCH  64
#define ISZ    512
#define HSZ    1024
#define GSZ    4096
#define NB     256
#define NT     256
#define PITCH  1032
#define SLAB   (16 * PITCH)

static constexpr size_t OFF_XPREV = (size_t)TSTEPS * BATCH * HSZ;
static constexpr size_t OFF_H     = OFF_XPREV + (size_t)BATCH * 1024;
static constexpr size_t OFF_HP    = OFF_H  + (size_t)BATCH * HSZ;
static constexpr size_t OFF_C     = OFF_HP + (size_t)BATCH * HSZ;
static constexpr size_t OFF_M     = OFF_C  + (size_t)BATCH * HSZ;
static constexpr size_t OFF_REG   = OFF_M  + (size_t)BATCH * GSZ;

#define TH_RAW 0.1f
#define TH_QNT 0.1015625f

__device__ __forceinline__ float qA(float x) {
  float v = rintf(x * 256.0f);
  v = fminf(fmaxf(v, -32768.0f), 32767.0f);
  return v * 0.00390625f;
}
__device__ __forceinline__ float qN(float x) {
  float v = rintf(x * 256.0f);
  v = fminf(fmaxf(v, -512.0f), 511.0f);
  return v * 0.00390625f;
}
__device__ __forceinline__ float sigm(float x) { return 1.0f / (1.0f + expf(-x)); }

// ---------------------------------------------------------------------------
__global__ __launch_bounds__(256) void xscan_kernel(const float* __restrict__ x,
                                                    float* __restrict__ dx,
                                                    float* __restrict__ out_xprev) {
  const int gid = blockIdx.x * blockDim.x + threadIdx.x;
  float xp = 0.0f;
  #pragma unroll 8
  for (int t = 0; t < TSTEPS; t++) {
    float xq = qA(x[(size_t)t * (BATCH * ISZ) + gid]);
    float d  = xq - xp;
    float da = fabsf(d);
    dx[(size_t)t * (BATCH * ISZ) + gid] = (da < TH_QNT) ? 0.0f : d;
    if (da >= TH_RAW) xp = xq;
  }
  const int b = gid >> 9;
  const int i = gid & 511;
  out_xprev[(size_t)b * 1024 + i]       = xp;
  out_xprev[(size_t)b * 1024 + 512 + i] = 0.0f;
}

// ---------------------------------------------------------------------------
// Grid barrier (validated r7/r8 semantics).
// ---------------------------------------------------------------------------
__device__ __forceinline__ void gbar(int* flags, int e) {
  asm volatile("s_waitcnt vmcnt(0)" ::: "memory");
  __syncthreads();
  if (threadIdx.x == 0) {
    __hip_atomic_store(&flags[blockIdx.x], e, __ATOMIC_RELAXED, __HIP_MEMORY_SCOPE_AGENT);
  }
  if (threadIdx.x < 64) {
    const ull_t* f64 = (const ull_t*)flags;
    const int l = threadIdx.x;
    bool done;
    do {
      ull_t a = __hip_atomic_load(f64 + l,      __ATOMIC_RELAXED, __HIP_MEMORY_SCOPE_AGENT);
      ull_t c = __hip_atomic_load(f64 + 64 + l, __ATOMIC_RELAXED, __HIP_MEMORY_SCOPE_AGENT);
      bool ok = ((int)a >= e) & ((int)(a >> 32) >= e) &
                ((int)c >= e) & ((int)(c >> 32) >= e);
      done = __all(ok);
      if (!done) __builtin_amdgcn_s_sleep(2);
    } while (!done);
  }
  __syncthreads();
}

// ---------------------------------------------------------------------------
// ABLATION PROBE (round-10: step counts sized so each lands in rocprof top-5;
// absence from top-5 => rate bound). MODE bits: 1=stage, 2=x-dot, 4=h-dot,
// 8=gates+dh-store. DCE guards per rule #17.
// ---------------------------------------------------------------------------
template <int MODE, int STEPS>
__global__ __launch_bounds__(NT, 1) void probe_kernel(
    const float* __restrict__ dx, const float* __restrict__ w_ih,
    const float* __restrict__ w_hh, const float* __restrict__ b_ih,
    const float* __restrict__ b_hh, float* __restrict__ dummy,
    __half* __restrict__ dh16, int* flags) {
  __shared__ __align__(16) __half dhs[4 * SLAB];

  const int tid  = threadIdx.x;
  const int wid  = tid >> 6;
  const int lane = tid & 63;
  const int jj   = tid & 3;
  const int b    = tid >> 2;
  const int lb   = b & 15;
  const int j    = blockIdx.x * 4 + jj;
  const int g0 = j, g1 = j + HSZ, g2 = j + 2 * HSZ, g3 = j + 3 * HSZ;
  const size_t DHBUF = (size_t)BATCH * HSZ;

  float m0 = b_ih[g0] + b_hh[g0];
  float m1 = b_ih[g1] + b_hh[g1];
  float m2 = b_ih[g2] + b_hh[g2];
  float m3 = b_ih[g3] + b_hh[g3];
  float c = 0.0f, hp = 0.0f, h = 0.0f, regacc = 0.0f;
  ull_t sink = 0;

  const float4* __restrict__ wi0 = (const float4*)(w_ih + (size_t)g0 * ISZ);
  const float4* __restrict__ wi1 = (const float4*)(w_ih + (size_t)g1 * ISZ);
  const float4* __restrict__ wi2 = (const float4*)(w_ih + (size_t)g2 * ISZ);
  const float4* __restrict__ wi3 = (const float4*)(w_ih + (size_t)g3 * ISZ);
  const float4* __restrict__ wh0 = (const float4*)(w_hh + (size_t)g0 * HSZ);
  const float4* __restrict__ wh1 = (const float4*)(w_hh + (size_t)g1 * HSZ);
  const float4* __restrict__ wh2 = (const float4*)(w_hh + (size_t)g2 * HSZ);
  const float4* __restrict__ wh3 = (const float4*)(w_hh + (size_t)g3 * HSZ);

  __half* slab = dhs + wid * SLAB;
  const __half* lrow = slab + lb * PITCH;
  int epoch = 1;

  for (int t = 0; t < STEPS; t++) {
    if constexpr (MODE & 1) {
      const ull_t* __restrict__ src =
          (const ull_t*)(dh16 + (size_t)(t & 1) * DHBUF) + (size_t)wid * 4096;
      #pragma unroll
      for (int r4 = 0; r4 < 16; r4 += 4) {
        ull_t v[16];
        #pragma unroll
        for (int rr = 0; rr < 4; ++rr)
          #pragma unroll
          for (int i = 0; i < 4; ++i)
            v[rr * 4 + i] = __hip_atomic_load(src + (r4 + rr) * 256 + i * 64 + lane,
                                              __ATOMIC_RELAXED, __HIP_MEMORY_SCOPE_AGENT);
        #pragma unroll
        for (int rr = 0; rr < 4; ++rr)
          #pragma unroll
          for (int i = 0; i < 4; ++i) {
            sink ^= v[rr * 4 + i];
            *(ull_t*)(slab + (r4 + rr) * PITCH + (i * 64 + lane) * 4) = v[rr * 4 + i];
          }
      }
      if (__half2float(((volatile __half*)lrow)[0]) == 12345.0f) dummy[0] = 1.0f;
    }

    float a0 = 0.f, a1 = 0.f, a2 = 0.f, a3 = 0.f;
    if constexpr (MODE & 2) {
      const float4* __restrict__ xr = (const float4*)(dx + ((size_t)t % TSTEPS * BATCH + b) * ISZ);
      #pragma unroll 8
      for (int k = 0; k < ISZ / 4; k++) {
        float4 xv = xr[k]; float4 wv;
        wv = wi0[k]; a0 = fmaf(xv.x, wv.x, fmaf(xv.y, wv.y, fmaf(xv.z, wv.z, fmaf(xv.w, wv.w, a0))));
        wv = wi1[k]; a1 = fmaf(xv.x, wv.x, fmaf(xv.y, wv.y, fmaf(xv.z, wv.z, fmaf(xv.w, wv.w, a1))));
        wv = wi2[k]; a2 = fmaf(xv.x, wv.x, fmaf(xv.y, wv.y, fmaf(xv.z, wv.z, fmaf(xv.w, wv.w, a2))));
        wv = wi3[k]; a3 = fmaf(xv.x, wv.x, fmaf(xv.y, wv.y, fmaf(xv.z, wv.z, fmaf(xv.w, wv.w, a3))));
      }
    }
    if constexpr (MODE & 4) {
      #pragma unroll 4
      for (int i = 0; i < 128; ++i) {
        uint4 u = *(const uint4*)(lrow + i * 8);
        float h0 = __half2float(__ushort_as_half((ushort_t)(u.x & 0xffff)));
        float h1 = __half2float(__ushort_as_half((ushort_t)(u.x >> 16)));
        float h2 = __half2float(__ushort_as_half((ushort_t)(u.y & 0xffff)));
        float h3 = __half2float(__ushort_as_half((ushort_t)(u.y >> 16)));
        float h4 = __half2float(__ushort_as_half((ushort_t)(u.z & 0xffff)));
        float h5 = __half2float(__ushort_as_half((ushort_t)(u.z >> 16)));
        float h6 = __half2float(__ushort_as_half((ushort_t)(u.w & 0xffff)));
        float h7 = __half2float(__ushort_as_half((ushort_t)(u.w >> 16)));
        const int wi = i * 2;
        float4 w;
        w = wh0[wi];     a0 = fmaf(h0, w.x, fmaf(h1, w.y, fmaf(h2, w.z, fmaf(h3, w.w, a0))));
        w = wh0[wi + 1]; a0 = fmaf(h4, w.x, fmaf(h5, w.y, fmaf(h6, w.z, fmaf(h7, w.w, a0))));
        w = wh1[wi];     a1 = fmaf(h0, w.x, fmaf(h1, w.y, fmaf(h2, w.z, fmaf(h3, w.w, a1))));
        w = wh1[wi + 1]; a1 = fmaf(h4, w.x, fmaf(h5, w.y, fmaf(h6, w.z, fmaf(h7, w.w, a1))));
        w = wh2[wi];     a2 = fmaf(h0, w.x, fmaf(h1, w.y, fmaf(h2, w.z, fmaf(h3, w.w, a2))));
        w = wh2[wi + 1]; a2 = fmaf(h4, w.x, fmaf(h5, w.y, fmaf(h6, w.z, fmaf(h7, w.w, a2))));
        w = wh3[wi];     a3 = fmaf(h0, w.x, fmaf(h1, w.y, fmaf(h2, w.z, fmaf(h3, w.w, a3))));
        w = wh3[wi + 1]; a3 = fmaf(h4, w.x, fmaf(h5, w.y, fmaf(h6, w.z, fmaf(h7, w.w, a3))));
      }
    }
    m0 += a0; m1 += a1; m2 += a2; m3 += a3;

    if constexpr (MODE & 8) {
      float pi = qA(m0), pf = qA(m1), pg = qA(m2), po = qA(m3);
      float gi = qN(sigm(pi));
      float gf = qN(sigm(pf));
      float gg = qN(tanhf(pg));
      float go = qN(sigm(po));
      float cn = c * gf + gi * gg;
      c = qA(cn);
      float ct = qN(tanhf(c));
      h = qA(go * ct);
      dummy[(size_t)b * HSZ + j] = h;
      if (t < STEPS - 1) {
        float d  = h - hp;
        float da = fabsf(d);
        float dm = (da < TH_QNT) ? 0.0f : d;
        if (da >= TH_RAW) hp = h;
        regacc += fabsf(dm);
        ushort_t my = __half_as_ushort(__float2half(dm));
        ushort_t other = (ushort_t)__shfl((int)my, tid ^ 1, 64);
        if ((tid & 1) == 0) {
          uint_t dw = (uint_t)my | ((uint_t)other << 16);
          uint_t* dhw = (uint_t*)(dh16 + (size_t)((t + 1) & 1) * DHBUF);
          __hip_atomic_store(&dhw[((size_t)b * HSZ + j) >> 1], dw,
                             __ATOMIC_RELAXED, __HIP_MEMORY_SCOPE_AGENT);
        }
      }
    }
    gbar(flags, epoch); epoch++;
  }
  dummy[(size_t)blockIdx.x * NT + tid] =
      m0 + m1 + m2 + m3 + h + hp + c + regacc + (float)(uint_t)(sink & 0xff);
}

// ---------------------------------------------------------------------------
// REAL kernel: byte-identical to round 8 (validated, absmax 0.1171875).
// ---------------------------------------------------------------------------
__global__ __launch_bounds__(NT, 1) void scan_kernel(
    const float* __restrict__ dx, const float* __restrict__ w_ih,
    const float* __restrict__ w_hh, const float* __restrict__ b_ih,
    const float* __restrict__ b_hh, float* __restrict__ out,
    __half* __restrict__ dh16, float* __restrict__ partials, int* flags) {
  __shared__ __align__(16) __half dhs[4 * SLAB];
  __shared__ float red[NT];

  const int tid  = threadIdx.x;
  const int wid  = tid >> 6;
  const int lane = tid & 63;
  const int jj   = tid & 3;
  const int b    = tid >> 2;
  const int lb   = b & 15;
  const int j    = blockIdx.x * 4 + jj;
  const int g0 = j, g1 = j + HSZ, g2 = j + 2 * HSZ, g3 = j + 3 * HSZ;
  const size_t DHBUF = (size_t)BATCH * HSZ;

  float m0 = b_ih[g0] + b_hh[g0];
  float m1 = b_ih[g1] + b_hh[g1];
  float m2 = b_ih[g2] + b_hh[g2];
  float m3 = b_ih[g3] + b_hh[g3];
  float c = 0.0f, hp = 0.0f, h = 0.0f, regacc = 0.0f;

  const float4* __restrict__ wi0 = (const float4*)(w_ih + (size_t)g0 * ISZ);
  const float4* __restrict__ wi1 = (const float4*)(w_ih + (size_t)g1 * ISZ);
  const float4* __restrict__ wi2 = (const float4*)(w_ih + (size_t)g2 * ISZ);
  const float4* __restrict__ wi3 = (const float4*)(w_ih + (size_t)g3 * ISZ);
  const float4* __restrict__ wh0 = (const float4*)(w_hh + (size_t)g0 * HSZ);
  const float4* __restrict__ wh1 = (const float4*)(w_hh + (size_t)g1 * HSZ);
  const float4* __restrict__ wh2 = (const float4*)(w_hh + (size_t)g2 * HSZ);
  const float4* __restrict__ wh3 = (const float4*)(w_hh + (size_t)g3 * HSZ);

  __half* slab = dhs + wid * SLAB;
  const __half* lrow = slab + lb * PITCH;
  int epoch = 1;

  for (int t = 0; t < TSTEPS; t++) {
    const ull_t* __restrict__ src =
        (const ull_t*)(dh16 + (size_t)(t & 1) * DHBUF) + (size_t)wid * 4096;
    #pragma unroll
    for (int r4 = 0; r4 < 16; r4 += 4) {
      ull_t v[16];
      #pragma unroll
      for (int rr = 0; rr < 4; ++rr)
        #pragma unroll
        for (int i = 0; i < 4; ++i)
          v[rr * 4 + i] = __hip_atomic_load(src + (r4 + rr) * 256 + i * 64 + lane,
                                            __ATOMIC_RELAXED, __HIP_MEMORY_SCOPE_AGENT);
      #pragma unroll
      for (int rr = 0; rr < 4; ++rr)
        #pragma unroll
        for (int i = 0; i < 4; ++i)
          *(ull_t*)(slab + (r4 + rr) * PITCH + (i * 64 + lane) * 4) = v[rr * 4 + i];
    }

    float a0 = 0.f, a1 = 0.f, a2 = 0.f, a3 = 0.f;
    {
      const float4* __restrict__ xr = (const float4*)(dx + ((size_t)t * BATCH + b) * ISZ);
      #pragma unroll 8
      for (int k = 0; k < ISZ / 4; k++) {
        float4 xv = xr[k]; float4 wv;
        wv = wi0[k]; a0 = fmaf(xv.x, wv.x, fmaf(xv.y, wv.y, fmaf(xv.z, wv.z, fmaf(xv.w, wv.w, a0))));
        wv = wi1[k]; a1 = fmaf(xv.x, wv.x, fmaf(xv.y, wv.y, fmaf(xv.z, wv.z, fmaf(xv.w, wv.w, a1))));
        wv = wi2[k]; a2 = fmaf(xv.x, wv.x, fmaf(xv.y, wv.y, fmaf(xv.z, wv.z, fmaf(xv.w, wv.w, a2))));
        wv = wi3[k]; a3 = fmaf(xv.x, wv.x, fmaf(xv.y, wv.y, fmaf(xv.z, wv.z, fmaf(xv.w, wv.w, a3))));
      }
    }
    {
      #pragma unroll 4
      for (int i = 0; i < 128; ++i) {
        uint4 u = *(const uint4*)(lrow + i * 8);
        float h0 = __half2float(__ushort_as_half((ushort_t)(u.x & 0xffff)));
        float h1 = __half2float(__ushort_as_half((ushort_t)(u.x >> 16)));
        float h2 = __half2float(__ushort_as_half((ushort_t)(u.y & 0xffff)));
        float h3 = __half2float(__ushort_as_half((ushort_t)(u.y >> 16)));
        float h4 = __half2float(__ushort_as_half((ushort_t)(u.z & 0xffff)));
        float h5 = __half2float(__ushort_as_half((ushort_t)(u.z >> 16)));
        float h6 = __half2float(__ushort_as_half((ushort_t)(u.w & 0xffff)));
        float h7 = __half2float(__ushort_as_half((ushort_t)(u.w >> 16)));
        const int wi = i * 2;
        float4 w;
        w = wh0[wi];     a0 = fmaf(h0, w.x, fmaf(h1, w.y, fmaf(h2, w.z, fmaf(h3, w.w, a0))));
        w = wh0[wi + 1]; a0 = fmaf(h4, w.x, fmaf(h5, w.y, fmaf(h6, w.z, fmaf(h7, w.w, a0))));
        w = wh1[wi];     a1 = fmaf(h0, w.x, fmaf(h1, w.y, fmaf(h2, w.z, fmaf(h3, w.w, a1))));
        w = wh1[wi + 1]; a1 = fmaf(h4, w.x, fmaf(h5, w.y, fmaf(h6, w.z, fmaf(h7, w.w, a1))));
        w = wh2[wi];     a2 = fmaf(h0, w.x, fmaf(h1, w.y, fmaf(h2, w.z, fmaf(h3, w.w, a2))));
        w = wh2[wi + 1]; a2 = fmaf(h4, w.x, fmaf(h5, w.y, fmaf(h6, w.z, fmaf(h7, w.w, a2))));
        w = wh3[wi];     a3 = fmaf(h0, w.x, fmaf(h1, w.y, fmaf(h2, w.z, fmaf(h3, w.w, a3))));
        w = wh3[wi + 1]; a3 = fmaf(h4, w.x, fmaf(h5, w.y, fmaf(h6, w.z, fmaf(h7, w.w, a3))));
      }
    }

    m0 += a0; m1 += a1; m2 += a2; m3 += a3;

    float pi = qA(m0), pf = qA(m1), pg = qA(m2), po = qA(m3);
    float gi = qN(sigm(pi));
    float gf = qN(sigm(pf));
    float gg = qN(tanhf(pg));
    float go = qN(sigm(po));
    float cn = c * gf + gi * gg;
    c = qA(cn);
    float ct = qN(tanhf(c));
    h = qA(go * ct);
    out[(size_t)t * (BATCH * HSZ) + (size_t)b * HSZ + j] = h;

    if (t < TSTEPS - 1) {
      float d  = h - hp;
      float da = fabsf(d);
      float dm = (da < TH_QNT) ? 0.0f : d;
      if (da >= TH_RAW) hp = h;
      regacc += fabsf(dm);
      ushort_t my = __half_as_ushort(__float2half(dm));
      ushort_t other = (ushort_t)__shfl((int)my, tid ^ 1, 64);
      if ((tid & 1) == 0) {
        uint_t dw = (uint_t)my | ((uint_t)other << 16);
        uint_t* dhw = (uint_t*)(dh16 + (size_t)((t + 1) & 1) * DHBUF);
        __hip_atomic_store(&dhw[((size_t)b * HSZ + j) >> 1], dw,
                           __ATOMIC_RELAXED, __HIP_MEMORY_SCOPE_AGENT);
      }
    }
    gbar(flags, epoch); epoch++;
  }

  out[OFF_H  + (size_t)b * HSZ + j] = h;
  out[OFF_HP + (size_t)b * HSZ + j] = hp;
  out[OFF_C  + (size_t)b * HSZ + j] = c;
  out[OFF_M  + (size_t)b * GSZ + g0] = m0;
  out[OFF_M  + (size_t)b * GSZ + g1] = m1;
  out[OFF_M  + (size_t)b * GSZ + g2] = m2;
  out[OFF_M  + (size_t)b * GSZ + g3] = m3;

  red[tid] = regacc;
  __syncthreads();
  for (int s = NT / 2; s > 0; s >>= 1) {
    if (tid < s) red[tid] += red[tid + s];
    __syncthreads();
  }
  if (tid == 0)
    __hip_atomic_store(&partials[blockIdx.x], red[0], __ATOMIC_RELAXED, __HIP_MEMORY_SCOPE_AGENT);
  gbar(flags, epoch); epoch++;
  if (blockIdx.x == 0) {
    red[tid] = __hip_atomic_load(&partials[tid], __ATOMIC_RELAXED, __HIP_MEMORY_SCOPE_AGENT);
    __syncthreads();
    for (int s = NT / 2; s > 0; s >>= 1) {
      if (tid < s) red[tid] += red[tid + s];
      __syncthreads();
    }
    if (tid == 0) out[OFF_REG] = red[0];
  }
}

// ---------------------------------------------------------------------------
extern "C" void kernel_launch(void* const* d_in, const int* in_sizes, int n_in,
                              void* d_out, int out_size, void* d_ws, size_t ws_size,
                              hipStream_t stream) {
  const float* x    = (const float*)d_in[0];
  const float* w_ih = (const float*)d_in[1];
  const float* w_hh = (const float*)d_in[2];
  const float* b_ih = (const float*)d_in[3];
  const float* b_hh = (const float*)d_in[4];
  float* out = (float*)d_out;

  const size_t dx_elems = (size_t)TSTEPS * BATCH * ISZ;
  float*  dx        = (float*)d_ws;
  __half* dh16      = (__half*)(dx + dx_elems);
  float*  partials  = (float*)(dh16 + 2 * (size_t)BATCH * HSZ);
  int*    flags     = (int*)(partials + NB);
  size_t needed_real = (size_t)((char*)(flags + NB) - (char*)d_ws);
  if (ws_size < needed_real) return;
  __half* dh16p     = (__half*)(flags + NB);
  int*    flagsp    = (int*)(dh16p + 2 * (size_t)BATCH * HSZ);   // 4 regions of NB ints
  float*  dummy     = (float*)(flagsp + 4 * NB);                 // B*H floats
  size_t needed_probe = (size_t)((char*)(dummy + (size_t)BATCH * HSZ) - (char*)d_ws);
  const bool do_probe = (ws_size >= needed_probe);

  (void)hipMemsetAsync(dh16, 0, 2 * (size_t)BATCH * HSZ * sizeof(__half), stream);
  (void)hipMemsetAsync(flags, 0, NB * sizeof(int), stream);
  if (do_probe) {
    (void)hipMemsetAsync(dh16p, 0, 2 * (size_t)BATCH * HSZ * sizeof(__half), stream);
    (void)hipMemsetAsync(flagsp, 0, 4 * NB * sizeof(int), stream);
  }

  xscan_kernel<<<128, 256, 0, stream>>>(x, dx, out + OFF_XPREV);

  if (do_probe) {
    // sized for top-5 visibility (scan ~90ms): steps chosen so any rate above
    // the per-probe threshold (90ms/steps) surfaces; absence => rate bound.
    probe_kernel<0, 32768><<<NB, NT, 0, stream>>>(dx, w_ih, w_hh, b_ih, b_hh,
                                                  dummy, dh16p, flagsp + 0 * NB);
    probe_kernel<1, 4096><<<NB, NT, 0, stream>>>(dx, w_ih, w_hh, b_ih, b_hh,
                                                 dummy, dh16p, flagsp + 1 * NB);
    probe_kernel<3, 2048><<<NB, NT, 0, stream>>>(dx, w_ih, w_hh, b_ih, b_hh,
                                                 dummy, dh16p, flagsp + 2 * NB);
    probe_kernel<7, 1024><<<NB, NT, 0, stream>>>(dx, w_ih, w_hh, b_ih, b_hh,
                                                 dummy, dh16p, flagsp + 3 * NB);
  }

  scan_kernel<<<NB, NT, 0, stream>>>(dx, w_ih, w_hh, b_ih, b_hh, out,
                                     dh16, partials, flags);
}

// Round 11
// 95086.774 us; speedup vs baseline: 5.6992x; 5.6992x over previous
//
#include <hip/hip_runtime.h>
#include <hip/hip_fp16.h>
#include <stdint.h>

typedef unsigned short ushort_t;
typedef unsigned int uint_t;
typedef unsigned long long ull_t;

#define TSTEPS 512
#define BATCH  64
#define ISZ    512
#define HSZ    1024
#define GSZ    4096
#define NB     256
#define NTH    1024   // 16 waves/block = 4 waves/SIMD (the occupancy fix)

static constexpr size_t OFF_XPREV = (size_t)TSTEPS * BATCH * HSZ;
static constexpr size_t OFF_H     = OFF_XPREV + (size_t)BATCH * 1024;
static constexpr size_t OFF_HP    = OFF_H  + (size_t)BATCH * HSZ;
static constexpr size_t OFF_C     = OFF_HP + (size_t)BATCH * HSZ;
static constexpr size_t OFF_M     = OFF_C  + (size_t)BATCH * HSZ;
static constexpr size_t OFF_REG   = OFF_M  + (size_t)BATCH * GSZ;

#define TH_RAW 0.1f
#define TH_QNT 0.1015625f

__device__ __forceinline__ float qA(float x) {
  float v = rintf(x * 256.0f);
  v = fminf(fmaxf(v, -32768.0f), 32767.0f);
  return v * 0.00390625f;
}
__device__ __forceinline__ float qN(float x) {
  float v = rintf(x * 256.0f);
  v = fminf(fmaxf(v, -512.0f), 511.0f);
  return v * 0.00390625f;
}
__device__ __forceinline__ float sigm(float x) { return 1.0f / (1.0f + expf(-x)); }

// ---------------------------------------------------------------------------
__global__ __launch_bounds__(256) void xscan_kernel(const float* __restrict__ x,
                                                    float* __restrict__ dx,
                                                    float* __restrict__ out_xprev) {
  const int gid = blockIdx.x * blockDim.x + threadIdx.x;
  float xp = 0.0f;
  #pragma unroll 8
  for (int t = 0; t < TSTEPS; t++) {
    float xq = qA(x[(size_t)t * (BATCH * ISZ) + gid]);
    float d  = xq - xp;
    float da = fabsf(d);
    dx[(size_t)t * (BATCH * ISZ) + gid] = (da < TH_QNT) ? 0.0f : d;
    if (da >= TH_RAW) xp = xq;
  }
  const int b = gid >> 9;
  const int i = gid & 511;
  out_xprev[(size_t)b * 1024 + i]       = xp;
  out_xprev[(size_t)b * 1024 + 512 + i] = 0.0f;
}

// ---------------------------------------------------------------------------
// Grid barrier (validated r7/r8 semantics): vmcnt drain -> RELAXED flag store;
// wave 0 polls all 256 flags via paired u64 relaxed agent loads.
// ---------------------------------------------------------------------------
__device__ __forceinline__ void gbar(int* flags, int e) {
  asm volatile("s_waitcnt vmcnt(0)" ::: "memory");
  __syncthreads();
  if (threadIdx.x == 0) {
    __hip_atomic_store(&flags[blockIdx.x], e, __ATOMIC_RELAXED, __HIP_MEMORY_SCOPE_AGENT);
  }
  if (threadIdx.x < 64) {
    const ull_t* f64 = (const ull_t*)flags;
    const int l = threadIdx.x;
    bool done;
    do {
      ull_t a = __hip_atomic_load(f64 + l,      __ATOMIC_RELAXED, __HIP_MEMORY_SCOPE_AGENT);
      ull_t c = __hip_atomic_load(f64 + 64 + l, __ATOMIC_RELAXED, __HIP_MEMORY_SCOPE_AGENT);
      bool ok = ((int)a >= e) & ((int)(a >> 32) >= e) &
                ((int)c >= e) & ((int)(c >> 32) >= e);
      done = __all(ok);
      if (!done) __builtin_amdgcn_s_sleep(2);
    } while (!done);
  }
  __syncthreads();
}

// ---------------------------------------------------------------------------
// Round-11 scan: 256 blocks x 1024 threads. Thread (b, jj, kq) computes the
// kq-quarter (k-split by 4) of the 4 gate dot products for site (b, j).
//   jj = tid&3, b = (tid>>2)&63, kq = tid>>8  (kq is wave-uniform).
// dh (fp16, 128KB) is staged to LDS by all 16 waves with an XOR swizzle;
// h-dot reads LDS only (zero VMEM). x/w loads are f32 cached VMEM, hidden by
// 4 waves/SIMD TLP. Quarters are combined in fixed order by waves 0-3
// (tid<256), which own all recurrent state / gates / dh production.
// ---------------------------------------------------------------------------
__global__ __launch_bounds__(NTH, 4) void scan_kernel(
    const float* __restrict__ dx, const float* __restrict__ w_ih,
    const float* __restrict__ w_hh, const float* __restrict__ b_ih,
    const float* __restrict__ b_hh, float* __restrict__ out,
    __half* __restrict__ dh16, float* __restrict__ partials, int* flags) {
  // LDS: dh slab 131072 B (64 rows x 2048 B, swizzled) | acc 16384 B
  __shared__ __align__(16) unsigned char lds[131072 + 16384];
  float4* __restrict__ accb = (float4*)(lds + 131072);

  const int tid  = threadIdx.x;
  const int jj   = tid & 3;
  const int b    = (tid >> 2) & 63;
  const int kq   = tid >> 8;          // 0..3, wave-uniform
  const int site = tid & 255;         // b*4 + jj
  const int j    = blockIdx.x * 4 + jj;
  const int g0 = j, g1 = j + HSZ, g2 = j + 2 * HSZ, g3 = j + 3 * HSZ;
  const size_t DHBUF = (size_t)BATCH * HSZ;

  // per-thread k-quarter weight bases
  const float4* __restrict__ wh0 = (const float4*)(w_hh + (size_t)g0 * HSZ + kq * 256);
  const float4* __restrict__ wh1 = (const float4*)(w_hh + (size_t)g1 * HSZ + kq * 256);
  const float4* __restrict__ wh2 = (const float4*)(w_hh + (size_t)g2 * HSZ + kq * 256);
  const float4* __restrict__ wh3 = (const float4*)(w_hh + (size_t)g3 * HSZ + kq * 256);
  const float4* __restrict__ wi0 = (const float4*)(w_ih + (size_t)g0 * ISZ + kq * 128);
  const float4* __restrict__ wi1 = (const float4*)(w_ih + (size_t)g1 * ISZ + kq * 128);
  const float4* __restrict__ wi2 = (const float4*)(w_ih + (size_t)g2 * ISZ + kq * 128);
  const float4* __restrict__ wi3 = (const float4*)(w_ih + (size_t)g3 * ISZ + kq * 128);

  // combiner (tid<256) recurrent state
  float m0 = 0.f, m1 = 0.f, m2 = 0.f, m3 = 0.f;
  float c = 0.0f, hp = 0.0f, h = 0.0f, regacc = 0.0f;
  if (tid < 256) {
    m0 = b_ih[g0] + b_hh[g0];
    m1 = b_ih[g1] + b_hh[g1];
    m2 = b_ih[g2] + b_hh[g2];
    m3 = b_ih[g3] + b_hh[g3];
  }

  // dh LDS read base: row b, quarter kq, XOR-swizzled (key = (b+4kq)&7)
  const unsigned char* __restrict__ dhb = lds + b * 2048;
  const int rbase = kq * 512;
  const int rkey  = ((b + 4 * kq) & 7) << 4;

  int epoch = 1;

  for (int t = 0; t < TSTEPS; t++) {
    { // ---- stage dh[t&1] -> LDS: 16384 u64, coalesced, swizzled ----------
      const ull_t* __restrict__ src = (const ull_t*)(dh16 + (size_t)(t & 1) * DHBUF);
      ull_t v[16];
      #pragma unroll
      for (int i = 0; i < 16; ++i)
        v[i] = __hip_atomic_load(src + i * 1024 + tid, __ATOMIC_RELAXED,
                                 __HIP_MEMORY_SCOPE_AGENT);
      #pragma unroll
      for (int i = 0; i < 16; ++i) {
        const int u   = i * 1024 + tid;   // u64 index
        const int row = u >> 8;
        const int c4  = u & 255;
        const int byt = row * 2048 + ((c4 * 8) ^ (((row + 4 * (c4 >> 6)) & 7) << 4));
        *(ull_t*)(lds + byt) = v[i];
      }
    }
    __syncthreads();  // staged rows visible to all waves

    float a0 = 0.f, a1 = 0.f, a2 = 0.f, a3 = 0.f;
    { // ---- x-dot quarter: 128 of 512 k ----------------------------------
      const float4* __restrict__ xr =
          (const float4*)(dx + ((size_t)t * BATCH + b) * ISZ + kq * 128);
      #pragma unroll 8
      for (int k = 0; k < 32; k++) {
        float4 xv = xr[k]; float4 wv;
        wv = wi0[k]; a0 = fmaf(xv.x, wv.x, fmaf(xv.y, wv.y, fmaf(xv.z, wv.z, fmaf(xv.w, wv.w, a0))));
        wv = wi1[k]; a1 = fmaf(xv.x, wv.x, fmaf(xv.y, wv.y, fmaf(xv.z, wv.z, fmaf(xv.w, wv.w, a1))));
        wv = wi2[k]; a2 = fmaf(xv.x, wv.x, fmaf(xv.y, wv.y, fmaf(xv.z, wv.z, fmaf(xv.w, wv.w, a2))));
        wv = wi3[k]; a3 = fmaf(xv.x, wv.x, fmaf(xv.y, wv.y, fmaf(xv.z, wv.z, fmaf(xv.w, wv.w, a3))));
      }
    }
    { // ---- h-dot quarter: 256 of 1024 k, dh from LDS (no VMEM for dh) ----
      #pragma unroll 4
      for (int ii = 0; ii < 32; ++ii) {
        uint4 u = *(const uint4*)(dhb + ((rbase + ii * 16) ^ rkey));
        float h0 = __half2float(__ushort_as_half((ushort_t)(u.x & 0xffff)));
        float h1 = __half2float(__ushort_as_half((ushort_t)(u.x >> 16)));
        float h2 = __half2float(__ushort_as_half((ushort_t)(u.y & 0xffff)));
        float h3 = __half2float(__ushort_as_half((ushort_t)(u.y >> 16)));
        float h4 = __half2float(__ushort_as_half((ushort_t)(u.z & 0xffff)));
        float h5 = __half2float(__ushort_as_half((ushort_t)(u.z >> 16)));
        float h6 = __half2float(__ushort_as_half((ushort_t)(u.w & 0xffff)));
        float h7 = __half2float(__ushort_as_half((ushort_t)(u.w >> 16)));
        const int wi = ii * 2;
        float4 w;
        w = wh0[wi];     a0 = fmaf(h0, w.x, fmaf(h1, w.y, fmaf(h2, w.z, fmaf(h3, w.w, a0))));
        w = wh0[wi + 1]; a0 = fmaf(h4, w.x, fmaf(h5, w.y, fmaf(h6, w.z, fmaf(h7, w.w, a0))));
        w = wh1[wi];     a1 = fmaf(h0, w.x, fmaf(h1, w.y, fmaf(h2, w.z, fmaf(h3, w.w, a1))));
        w = wh1[wi + 1]; a1 = fmaf(h4, w.x, fmaf(h5, w.y, fmaf(h6, w.z, fmaf(h7, w.w, a1))));
        w = wh2[wi];     a2 = fmaf(h0, w.x, fmaf(h1, w.y, fmaf(h2, w.z, fmaf(h3, w.w, a2))));
        w = wh2[wi + 1]; a2 = fmaf(h4, w.x, fmaf(h5, w.y, fmaf(h6, w.z, fmaf(h7, w.w, a2))));
        w = wh3[wi];     a3 = fmaf(h0, w.x, fmaf(h1, w.y, fmaf(h2, w.z, fmaf(h3, w.w, a3))));
        w = wh3[wi + 1]; a3 = fmaf(h4, w.x, fmaf(h5, w.y, fmaf(h6, w.z, fmaf(h7, w.w, a3))));
      }
    }

    accb[kq * 256 + site] = make_float4(a0, a1, a2, a3);
    __syncthreads();

    if (tid < 256) {  // ---- combine quarters (fixed order) + gates --------
      float4 s0 = accb[tid];
      float4 s1 = accb[256 + tid];
      float4 s2 = accb[512 + tid];
      float4 s3 = accb[768 + tid];
      m0 += s0.x + s1.x + s2.x + s3.x;
      m1 += s0.y + s1.y + s2.y + s3.y;
      m2 += s0.z + s1.z + s2.z + s3.z;
      m3 += s0.w + s1.w + s2.w + s3.w;

      float pi = qA(m0), pf = qA(m1), pg = qA(m2), po = qA(m3);
      float gi = qN(sigm(pi));
      float gf = qN(sigm(pf));
      float gg = qN(tanhf(pg));
      float go = qN(sigm(po));
      float cn = c * gf + gi * gg;
      c = qA(cn);
      float ct = qN(tanhf(c));
      h = qA(go * ct);
      out[(size_t)t * (BATCH * HSZ) + (size_t)b * HSZ + j] = h;

      if (t < TSTEPS - 1) {
        float d  = h - hp;
        float da = fabsf(d);
        float dm = (da < TH_QNT) ? 0.0f : d;
        if (da >= TH_RAW) hp = h;
        regacc += fabsf(dm);
        ushort_t my = __half_as_ushort(__float2half(dm));     // fp16 exact for dh
        ushort_t other = (ushort_t)__shfl((int)my, tid ^ 1, 64);
        if ((jj & 1) == 0) {
          uint_t dw = (uint_t)my | ((uint_t)other << 16);
          uint_t* dhw = (uint_t*)(dh16 + (size_t)((t + 1) & 1) * DHBUF);
          __hip_atomic_store(&dhw[((size_t)b * HSZ + j) >> 1], dw,
                             __ATOMIC_RELAXED, __HIP_MEMORY_SCOPE_AGENT);
        }
      }
    }
    gbar(flags, epoch); epoch++;
  }

  if (tid < 256) {  // final state dump
    out[OFF_H  + (size_t)b * HSZ + j] = h;
    out[OFF_HP + (size_t)b * HSZ + j] = hp;
    out[OFF_C  + (size_t)b * HSZ + j] = c;
    out[OFF_M  + (size_t)b * GSZ + g0] = m0;
    out[OFF_M  + (size_t)b * GSZ + g1] = m1;
    out[OFF_M  + (size_t)b * GSZ + g2] = m2;
    out[OFF_M  + (size_t)b * GSZ + g3] = m3;
  }

  // deterministic reg reduction (reuse LDS; dh slab no longer read)
  float* rf = (float*)lds;
  __syncthreads();
  if (tid < 256) rf[tid] = regacc;
  __syncthreads();
  for (int s = 128; s > 0; s >>= 1) {
    if (tid < s) rf[tid] += rf[tid + s];
    __syncthreads();
  }
  if (tid == 0)
    __hip_atomic_store(&partials[blockIdx.x], rf[0], __ATOMIC_RELAXED, __HIP_MEMORY_SCOPE_AGENT);
  gbar(flags, epoch); epoch++;
  if (blockIdx.x == 0) {
    if (tid < 256)
      rf[tid] = __hip_atomic_load(&partials[tid], __ATOMIC_RELAXED, __HIP_MEMORY_SCOPE_AGENT);
    __syncthreads();
    for (int s = 128; s > 0; s >>= 1) {
      if (tid < s) rf[tid] += rf[tid + s];
      __syncthreads();
    }
    if (tid == 0) out[OFF_REG] = rf[0];
  }
}

// ---------------------------------------------------------------------------
extern "C" void kernel_launch(void* const* d_in, const int* in_sizes, int n_in,
                              void* d_out, int out_size, void* d_ws, size_t ws_size,
                              hipStream_t stream) {
  const float* x    = (const float*)d_in[0];
  const float* w_ih = (const float*)d_in[1];
  const float* w_hh = (const float*)d_in[2];
  const float* b_ih = (const float*)d_in[3];
  const float* b_hh = (const float*)d_in[4];
  float* out = (float*)d_out;

  const size_t dx_elems = (size_t)TSTEPS * BATCH * ISZ;
  float*  dx       = (float*)d_ws;
  __half* dh16     = (__half*)(dx + dx_elems);
  float*  partials = (float*)(dh16 + 2 * (size_t)BATCH * HSZ);
  int*    flags    = (int*)(partials + NB);
  size_t needed = (size_t)((char*)(flags + NB) - (char*)d_ws);
  if (ws_size < needed) return;

  (void)hipMemsetAsync(dh16, 0, 2 * (size_t)BATCH * HSZ * sizeof(__half), stream);
  (void)hipMemsetAsync(flags, 0, NB * sizeof(int), stream);
  xscan_kernel<<<128, 256, 0, stream>>>(x, dx, out + OFF_XPREV);
  scan_kernel<<<NB, NTH, 0, stream>>>(dx, w_ih, w_hh, b_ih, b_hh, out,
                                      dh16, partials, flags);
}

// Round 12
// 5677.880 us; speedup vs baseline: 95.4433x; 16.7469x over previous
//
#include <hip/hip_runtime.h>
#include <hip/hip_fp16.h>
#include <stdint.h>

typedef unsigned short ushort_t;
typedef unsigned int uint_t;
typedef unsigned long long ull_t;
typedef _Float16 half8 __attribute__((ext_vector_type(8)));
typedef float f32x4 __attribute__((ext_vector_type(4)));

#define TSTEPS 512
#define BATCH  64
#define ISZ    512
#define HSZ    1024
#define GSZ    4096
#define NB     256
#define NTH    1024   // 16 waves = 4 b-tiles x 4 k-groups

static constexpr size_t OFF_XPREV = (size_t)TSTEPS * BATCH * HSZ;
static constexpr size_t OFF_H     = OFF_XPREV + (size_t)BATCH * 1024;
static constexpr size_t OFF_HP    = OFF_H  + (size_t)BATCH * HSZ;
static constexpr size_t OFF_C     = OFF_HP + (size_t)BATCH * HSZ;
static constexpr size_t OFF_M     = OFF_C  + (size_t)BATCH * HSZ;
static constexpr size_t OFF_REG   = OFF_M  + (size_t)BATCH * GSZ;

#define TH_RAW 0.1f
#define TH_QNT 0.1015625f

__device__ __forceinline__ float qA(float x) {
  float v = rintf(x * 256.0f);
  v = fminf(fmaxf(v, -32768.0f), 32767.0f);
  return v * 0.00390625f;
}
__device__ __forceinline__ float qN(float x) {
  float v = rintf(x * 256.0f);
  v = fminf(fmaxf(v, -512.0f), 511.0f);
  return v * 0.00390625f;
}
__device__ __forceinline__ float sigm(float x) { return 1.0f / (1.0f + expf(-x)); }

// ---------------------------------------------------------------------------
// Phase A: x-delta scan (exact f32 fixed-point). Now emits dx in fp16
// (exact except the rare |dx|>8, sub-quantum effect on a chaotic system).
// ---------------------------------------------------------------------------
__global__ __launch_bounds__(256) void xscan_kernel(const float* __restrict__ x,
                                                    __half* __restrict__ dx16,
                                                    float* __restrict__ out_xprev) {
  const int gid = blockIdx.x * blockDim.x + threadIdx.x;
  float xp = 0.0f;
  #pragma unroll 8
  for (int t = 0; t < TSTEPS; t++) {
    float xq = qA(x[(size_t)t * (BATCH * ISZ) + gid]);
    float d  = xq - xp;
    float da = fabsf(d);
    dx16[(size_t)t * (BATCH * ISZ) + gid] = __float2half((da < TH_QNT) ? 0.0f : d);
    if (da >= TH_RAW) xp = xq;
  }
  const int b = gid >> 9;
  const int i = gid & 511;
  out_xprev[(size_t)b * 1024 + i]       = xp;
  out_xprev[(size_t)b * 1024 + 512 + i] = 0.0f;
}

// ---------------------------------------------------------------------------
// Grid barrier (validated r7/r8/r11 semantics).
// ---------------------------------------------------------------------------
__device__ __forceinline__ void gbar(int* flags, int e) {
  asm volatile("s_waitcnt vmcnt(0)" ::: "memory");
  __syncthreads();
  if (threadIdx.x == 0) {
    __hip_atomic_store(&flags[blockIdx.x], e, __ATOMIC_RELAXED, __HIP_MEMORY_SCOPE_AGENT);
  }
  if (threadIdx.x < 64) {
    const ull_t* f64 = (const ull_t*)flags;
    const int l = threadIdx.x;
    bool done;
    do {
      ull_t a = __hip_atomic_load(f64 + l,      __ATOMIC_RELAXED, __HIP_MEMORY_SCOPE_AGENT);
      ull_t c = __hip_atomic_load(f64 + 64 + l, __ATOMIC_RELAXED, __HIP_MEMORY_SCOPE_AGENT);
      bool ok = ((int)a >= e) & ((int)(a >> 32) >= e) &
                ((int)c >= e) & ((int)(c >> 32) >= e);
      done = __all(ok);
      if (!done) __builtin_amdgcn_s_sleep(2);
    } while (!done);
  }
  __syncthreads();
}

// ---------------------------------------------------------------------------
// Round-12 scan: REGISTER-RESIDENT WEIGHTS + MFMA.
// Block = 16 gate-cols (4 j x 4 gates), grid-col n = gate*4 + jj.
// 16 waves = (bt: 4 b-tiles of 16) x (kg: 4 k-groups). Wave holds 12 fp16
// B-fragments of W (4 x-ktiles + 8 h-ktiles = 48 VGPR) loaded ONCE.
// Step: stage dx16[t] (64KB) -> slab -> 4 MFMA; stage dh16 (128KB) -> slab
// -> 8 MFMA; acc -> LDS partials -> 256 combiner threads (fixed-order sum,
// gates, h, dh-production: identical r11 semantics).
// Zero non-coalesced VMEM in the step loop.
// ---------------------------------------------------------------------------
__global__ __launch_bounds__(NTH, 4) void scan_kernel(
    const __half* __restrict__ dx16, const float* __restrict__ w_ih,
    const float* __restrict__ w_hh, const float* __restrict__ b_ih,
    const float* __restrict__ b_hh, float* __restrict__ out,
    __half* __restrict__ dh16, float* __restrict__ partials, int* flags) {
  __shared__ __align__(16) unsigned char slab[131072];   // dx(64KB)/dh(128KB) two-pass
  __shared__ float part[4][64][16];                      // 16 KB partials
  __shared__ float red[256];

  const int tid  = threadIdx.x;
  const int wid  = tid >> 6;
  const int lane = tid & 63;
  const int bt   = wid >> 2;          // b-tile 0..3
  const int kg   = wid & 3;           // k-group 0..3
  const int lr   = lane & 15;         // fragment row/col index
  const int lkb  = (lane >> 4) * 16;  // k-chunk byte offset (8 halves)
  const size_t DHBUF = (size_t)BATCH * HSZ;

  // ---- one-time: preload W fragments (fp16) into registers ---------------
  // B-frag for col n = lane&15: reads weight row wrow(n), k-contiguous 8.
  const int wrow = blockIdx.x * 4 + (lr & 3) + (lr >> 2) * HSZ;
  half8 wx[4], wh[8];
  #pragma unroll
  for (int kt = 0; kt < 4; ++kt) {
    const float* p = w_ih + (size_t)wrow * ISZ + kg * 128 + kt * 32 + (lane >> 4) * 8;
    half8 v;
    #pragma unroll
    for (int e = 0; e < 8; ++e) v[e] = (_Float16)p[e];
    wx[kt] = v;
  }
  #pragma unroll
  for (int kt = 0; kt < 8; ++kt) {
    const float* p = w_hh + (size_t)wrow * HSZ + kg * 256 + kt * 32 + (lane >> 4) * 8;
    half8 v;
    #pragma unroll
    for (int e = 0; e < 8; ++e) v[e] = (_Float16)p[e];
    wh[kt] = v;
  }

  // combiner state (tid<256): site s=tid, b=s>>2, jj=s&3
  const int jj = tid & 3;
  const int cb = tid >> 2;
  const int j  = blockIdx.x * 4 + jj;
  const int g0 = j, g1 = j + HSZ, g2 = j + 2 * HSZ, g3 = j + 3 * HSZ;
  float m0 = 0.f, m1 = 0.f, m2 = 0.f, m3 = 0.f;
  float c = 0.0f, hp = 0.0f, h = 0.0f, regacc = 0.0f;
  if (tid < 256) {
    m0 = b_ih[g0] + b_hh[g0];
    m1 = b_ih[g1] + b_hh[g1];
    m2 = b_ih[g2] + b_hh[g2];
    m3 = b_ih[g3] + b_hh[g3];
  }

  // A-fragment LDS read bases (row = bt*16 + lr)
  const int arow = bt * 16 + lr;
  const int akey = (arow & 7) << 4;
  const unsigned char* xbase = slab + arow * 1024;   // dx rows: 1024 B
  const unsigned char* hbase = slab + arow * 2048;   // dh rows: 2048 B

  int epoch = 1;

  for (int t = 0; t < TSTEPS; t++) {
    f32x4 acc = {0.f, 0.f, 0.f, 0.f};

    { // ---- stage dx16[t] -> slab (64KB, coalesced, swizzled) -------------
      const ull_t* __restrict__ sx = (const ull_t*)(dx16 + (size_t)t * (BATCH * ISZ));
      #pragma unroll
      for (int i2 = 0; i2 < 8; i2 += 4) {
        ull_t v[4];
        #pragma unroll
        for (int i = 0; i < 4; ++i) v[i] = sx[(i2 + i) * 1024 + tid];
        #pragma unroll
        for (int i = 0; i < 4; ++i) {
          const int u = (i2 + i) * 1024 + tid;
          const int row = u >> 7, cc = u & 127;
          *(ull_t*)(slab + row * 1024 + ((cc * 8) ^ ((row & 7) << 4))) = v[i];
        }
      }
    }
    __syncthreads();

    { // ---- x-pass: 4 MFMA ------------------------------------------------
      #pragma unroll
      for (int kt = 0; kt < 4; ++kt) {
        const int col = kg * 256 + kt * 64 + lkb;
        union { uint4 u; half8 hv; } U;
        U.u = *(const uint4*)(xbase + (col ^ akey));
        acc = __builtin_amdgcn_mfma_f32_16x16x32_f16(U.hv, wx[kt], acc, 0, 0, 0);
      }
    }
    __syncthreads();  // x-reads done before slab overwrite

    { // ---- stage dh16[t&1] -> slab (128KB, coalesced sc-loads, swizzled) --
      const ull_t* __restrict__ sh = (const ull_t*)(dh16 + (size_t)(t & 1) * DHBUF);
      #pragma unroll
      for (int i2 = 0; i2 < 16; i2 += 4) {
        ull_t v[4];
        #pragma unroll
        for (int i = 0; i < 4; ++i)
          v[i] = __hip_atomic_load(sh + (i2 + i) * 1024 + tid,
                                   __ATOMIC_RELAXED, __HIP_MEMORY_SCOPE_AGENT);
        #pragma unroll
        for (int i = 0; i < 4; ++i) {
          const int u = (i2 + i) * 1024 + tid;
          const int row = u >> 8, cc = u & 255;
          *(ull_t*)(slab + row * 2048 + ((cc * 8) ^ ((row & 7) << 4))) = v[i];
        }
      }
    }
    __syncthreads();

    { // ---- h-pass: 8 MFMA ------------------------------------------------
      #pragma unroll
      for (int kt = 0; kt < 8; ++kt) {
        const int col = kg * 512 + kt * 64 + lkb;
        union { uint4 u; half8 hv; } U;
        U.u = *(const uint4*)(hbase + (col ^ akey));
        acc = __builtin_amdgcn_mfma_f32_16x16x32_f16(U.hv, wh[kt], acc, 0, 0, 0);
      }
    }

    // ---- partials: D layout col=lane&15, row=(lane>>4)*4+r ----------------
    #pragma unroll
    for (int r = 0; r < 4; ++r)
      part[kg][bt * 16 + (lane >> 4) * 4 + r][lr] = acc[r];
    __syncthreads();

    if (tid < 256) {  // ---- combine (fixed order) + gates + dh ------------
      float s0 = 0.f, s1 = 0.f, s2 = 0.f, s3 = 0.f;
      #pragma unroll
      for (int k2 = 0; k2 < 4; ++k2) {
        s0 += part[k2][cb][jj];
        s1 += part[k2][cb][4 + jj];
        s2 += part[k2][cb][8 + jj];
        s3 += part[k2][cb][12 + jj];
      }
      m0 += s0; m1 += s1; m2 += s2; m3 += s3;

      float pi = qA(m0), pf = qA(m1), pg = qA(m2), po = qA(m3);
      float gi = qN(sigm(pi));
      float gf = qN(sigm(pf));
      float gg = qN(tanhf(pg));
      float go = qN(sigm(po));
      float cn = c * gf + gi * gg;
      c = qA(cn);
      float ct = qN(tanhf(c));
      h = qA(go * ct);
      out[(size_t)t * (BATCH * HSZ) + (size_t)cb * HSZ + j] = h;

      if (t < TSTEPS - 1) {
        float d  = h - hp;
        float da = fabsf(d);
        float dm = (da < TH_QNT) ? 0.0f : d;
        if (da >= TH_RAW) hp = h;
        regacc += fabsf(dm);
        ushort_t my = __half_as_ushort(__float2half(dm));   // fp16 exact for dh
        ushort_t other = (ushort_t)__shfl((int)my, tid ^ 1, 64);
        if ((jj & 1) == 0) {
          uint_t dw = (uint_t)my | ((uint_t)other << 16);
          uint_t* dhw = (uint_t*)(dh16 + (size_t)((t + 1) & 1) * DHBUF);
          __hip_atomic_store(&dhw[((size_t)cb * HSZ + j) >> 1], dw,
                             __ATOMIC_RELAXED, __HIP_MEMORY_SCOPE_AGENT);
        }
      }
    }
    gbar(flags, epoch); epoch++;
  }

  if (tid < 256) {  // final state dump (m carry is exact f32)
    out[OFF_H  + (size_t)cb * HSZ + j] = h;
    out[OFF_HP + (size_t)cb * HSZ + j] = hp;
    out[OFF_C  + (size_t)cb * HSZ + j] = c;
    out[OFF_M  + (size_t)cb * GSZ + g0] = m0;
    out[OFF_M  + (size_t)cb * GSZ + g1] = m1;
    out[OFF_M  + (size_t)cb * GSZ + g2] = m2;
    out[OFF_M  + (size_t)cb * GSZ + g3] = m3;
  }

  // deterministic reg reduction
  if (tid < 256) red[tid] = regacc;
  __syncthreads();
  for (int s = 128; s > 0; s >>= 1) {
    if (tid < s) red[tid] += red[tid + s];
    __syncthreads();
  }
  if (tid == 0)
    __hip_atomic_store(&partials[blockIdx.x], red[0], __ATOMIC_RELAXED, __HIP_MEMORY_SCOPE_AGENT);
  gbar(flags, epoch); epoch++;
  if (blockIdx.x == 0) {
    if (tid < 256)
      red[tid] = __hip_atomic_load(&partials[tid], __ATOMIC_RELAXED, __HIP_MEMORY_SCOPE_AGENT);
    __syncthreads();
    for (int s = 128; s > 0; s >>= 1) {
      if (tid < s) red[tid] += red[tid + s];
      __syncthreads();
    }
    if (tid == 0) out[OFF_REG] = red[0];
  }
}

// ---------------------------------------------------------------------------
extern "C" void kernel_launch(void* const* d_in, const int* in_sizes, int n_in,
                              void* d_out, int out_size, void* d_ws, size_t ws_size,
                              hipStream_t stream) {
  const float* x    = (const float*)d_in[0];
  const float* w_ih = (const float*)d_in[1];
  const float* w_hh = (const float*)d_in[2];
  const float* b_ih = (const float*)d_in[3];
  const float* b_hh = (const float*)d_in[4];
  float* out = (float*)d_out;

  const size_t dx_elems = (size_t)TSTEPS * BATCH * ISZ;   // fp16 now: 33.5 MB
  __half* dx16     = (__half*)d_ws;
  __half* dh16     = dx16 + dx_elems;
  float*  partials = (float*)(dh16 + 2 * (size_t)BATCH * HSZ);
  int*    flags    = (int*)(partials + NB);
  size_t needed = (size_t)((char*)(flags + NB) - (char*)d_ws);
  if (ws_size < needed) return;

  (void)hipMemsetAsync(dh16, 0, 2 * (size_t)BATCH * HSZ * sizeof(__half), stream);
  (void)hipMemsetAsync(flags, 0, NB * sizeof(int), stream);
  xscan_kernel<<<128, 256, 0, stream>>>(x, dx16, out + OFF_XPREV);
  scan_kernel<<<NB, NTH, 0, stream>>>(dx16, w_ih, w_hh, b_ih, b_hh, out,
                                      dh16, partials, flags);
}

// Round 13
// 2660.346 us; speedup vs baseline: 203.7012x; 2.1343x over previous
//
#include <hip/hip_runtime.h>
#include <hip/hip_fp16.h>
#include <stdint.h>

typedef unsigned short ushort_t;
typedef unsigned int uint_t;
typedef unsigned long long ull_t;
typedef _Float16 half8 __attribute__((ext_vector_type(8)));
typedef float f32x4 __attribute__((ext_vector_type(4)));

#define TSTEPS 512
#define BATCH  64
#define ISZ    512
#define HSZ    1024
#define GSZ    4096
#define NB     256
#define NTH    1024   // 16 waves = 4 b-tiles x 4 k-groups
#define DHFRAG 65536  // halves per dh fragment buffer (128 KB)

static constexpr size_t OFF_XPREV = (size_t)TSTEPS * BATCH * HSZ;
static constexpr size_t OFF_H     = OFF_XPREV + (size_t)BATCH * 1024;
static constexpr size_t OFF_HP    = OFF_H  + (size_t)BATCH * HSZ;
static constexpr size_t OFF_C     = OFF_HP + (size_t)BATCH * HSZ;
static constexpr size_t OFF_M     = OFF_C  + (size_t)BATCH * HSZ;
static constexpr size_t OFF_REG   = OFF_M  + (size_t)BATCH * GSZ;

#define TH_RAW 0.1f
#define TH_QNT 0.1015625f

__device__ __forceinline__ float qA(float x) {
  float v = rintf(x * 256.0f);
  v = fminf(fmaxf(v, -32768.0f), 32767.0f);
  return v * 0.00390625f;
}
__device__ __forceinline__ float qN(float x) {
  float v = rintf(x * 256.0f);
  v = fminf(fmaxf(v, -512.0f), 511.0f);
  return v * 0.00390625f;
}
__device__ __forceinline__ float sigm(float x) { return 1.0f / (1.0f + expf(-x)); }

// ---------------------------------------------------------------------------
// Phase A: x-delta scan (exact fixed-point); emits dx fp16, flat [t][b][i].
// ---------------------------------------------------------------------------
__global__ __launch_bounds__(256) void xscan_kernel(const float* __restrict__ x,
                                                    __half* __restrict__ dx16,
                                                    float* __restrict__ out_xprev) {
  const int gid = blockIdx.x * blockDim.x + threadIdx.x;
  float xp = 0.0f;
  #pragma unroll 8
  for (int t = 0; t < TSTEPS; t++) {
    float xq = qA(x[(size_t)t * (BATCH * ISZ) + gid]);
    float d  = xq - xp;
    float da = fabsf(d);
    dx16[(size_t)t * (BATCH * ISZ) + gid] = __float2half((da < TH_QNT) ? 0.0f : d);
    if (da >= TH_RAW) xp = xq;
  }
  const int b = gid >> 9;
  const int i = gid & 511;
  out_xprev[(size_t)b * 1024 + i]       = xp;
  out_xprev[(size_t)b * 1024 + 512 + i] = 0.0f;
}

// ---------------------------------------------------------------------------
// Split grid barrier (validated r7..r12 semantics): arrive = vmcnt drain ->
// sync -> relaxed flag store; wait = wave-0 poll -> sync. Work placed between
// arrive and wait runs in the barrier-wait shadow.
// ---------------------------------------------------------------------------
__device__ __forceinline__ void gbar_arrive(int* flags, int e) {
  asm volatile("s_waitcnt vmcnt(0)" ::: "memory");
  __syncthreads();
  if (threadIdx.x == 0) {
    __hip_atomic_store(&flags[blockIdx.x], e, __ATOMIC_RELAXED, __HIP_MEMORY_SCOPE_AGENT);
  }
}
__device__ __forceinline__ void gbar_wait(int* flags, int e) {
  if (threadIdx.x < 64) {
    const ull_t* f64 = (const ull_t*)flags;
    const int l = threadIdx.x;
    bool done;
    do {
      ull_t a = __hip_atomic_load(f64 + l,      __ATOMIC_RELAXED, __HIP_MEMORY_SCOPE_AGENT);
      ull_t c = __hip_atomic_load(f64 + 64 + l, __ATOMIC_RELAXED, __HIP_MEMORY_SCOPE_AGENT);
      bool ok = ((int)a >= e) & ((int)(a >> 32) >= e) &
                ((int)c >= e) & ((int)(c >> 32) >= e);
      done = __all(ok);
      if (!done) __builtin_amdgcn_s_sleep(2);
    } while (!done);
  }
  __syncthreads();
}

// ---------------------------------------------------------------------------
// Round-13 scan: register weights + MFMA (r12, validated) with
//  - dh in MFMA-FRAGMENT layout in global: cell (kc= k>>3, b) of 8 halves at
//    byte (kc*64+b)*16. h-pass reads fragments directly via coalesced 2xu64
//    relaxed agent loads (no LDS round-trip, no swizzle, no extra sync).
//  - dx LDS double-buffer: stage t+1 between gbar_arrive and gbar_wait.
// MFMA order identical to r12 -> bit-identical trajectory expected.
// ---------------------------------------------------------------------------
__global__ __launch_bounds__(NTH, 4) void scan_kernel(
    const __half* __restrict__ dx16, const float* __restrict__ w_ih,
    const float* __restrict__ w_hh, const float* __restrict__ b_ih,
    const float* __restrict__ b_hh, float* __restrict__ out,
    __half* __restrict__ dh16, float* __restrict__ partials, int* flags) {
  __shared__ __align__(16) unsigned char dxbuf[2][65536];  // dx double buffer
  __shared__ float part[4][64][16];
  __shared__ float red[256];

  const int tid  = threadIdx.x;
  const int wid  = tid >> 6;
  const int lane = tid & 63;
  const int bt   = wid >> 2;          // b-tile 0..3
  const int kg   = wid & 3;           // k-group 0..3
  const int lr   = lane & 15;
  const int lkb  = (lane >> 4) * 16;  // byte offset of k-chunk in LDS row

  // ---- one-time: W fragments (fp16) into registers (identical to r12) ----
  const int wrow = blockIdx.x * 4 + (lr & 3) + (lr >> 2) * HSZ;
  half8 wx[4], wh[8];
  #pragma unroll
  for (int kt = 0; kt < 4; ++kt) {
    const float* p = w_ih + (size_t)wrow * ISZ + kg * 128 + kt * 32 + (lane >> 4) * 8;
    half8 v;
    #pragma unroll
    for (int e = 0; e < 8; ++e) v[e] = (_Float16)p[e];
    wx[kt] = v;
  }
  #pragma unroll
  for (int kt = 0; kt < 8; ++kt) {
    const float* p = w_hh + (size_t)wrow * HSZ + kg * 256 + kt * 32 + (lane >> 4) * 8;
    half8 v;
    #pragma unroll
    for (int e = 0; e < 8; ++e) v[e] = (_Float16)p[e];
    wh[kt] = v;
  }

  // combiner state (tid<256)
  const int jj = tid & 3;
  const int cb = tid >> 2;
  const int j  = blockIdx.x * 4 + jj;
  const int g0 = j, g1 = j + HSZ, g2 = j + 2 * HSZ, g3 = j + 3 * HSZ;
  float m0 = 0.f, m1 = 0.f, m2 = 0.f, m3 = 0.f;
  float c = 0.0f, hp = 0.0f, h = 0.0f, regacc = 0.0f;
  if (tid < 256) {
    m0 = b_ih[g0] + b_hh[g0];
    m1 = b_ih[g1] + b_hh[g1];
    m2 = b_ih[g2] + b_hh[g2];
    m3 = b_ih[g3] + b_hh[g3];
  }
  // combiner dh-frag cell: kc = j>>3 = blockIdx>>1; ull idx = cell*2 + (bI&1)
  const size_t dhcell2 = ((size_t)(blockIdx.x >> 1) * 64 + cb) * 2 + (blockIdx.x & 1);

  // A-fragment LDS read base for dx (row = bt*16 + lr)
  const int arow = bt * 16 + lr;
  const int akey = (arow & 7) << 4;

  // h-fragment global cell base: kc(kt) = kg*32 + kt*4 + (lane>>4), b = arow
  const int kc0 = kg * 32 + (lane >> 4);
  const int hrow = arow;

  // ---- stage dx[0] ----
  {
    const ull_t* __restrict__ sx = (const ull_t*)dx16;
    #pragma unroll
    for (int i = 0; i < 8; ++i) {
      ull_t v = sx[i * 1024 + tid];
      const int u = i * 1024 + tid;
      const int row = u >> 7, cc = u & 127;
      *(ull_t*)(&dxbuf[0][0] + row * 1024 + ((cc * 8) ^ ((row & 7) << 4))) = v;
    }
  }
  __syncthreads();

  int epoch = 1;

  for (int t = 0; t < TSTEPS; t++) {
    const ull_t* __restrict__ hb = (const ull_t*)(dh16 + (size_t)(t & 1) * DHFRAG);
    const unsigned char* xbase = &dxbuf[t & 1][0] + arow * 1024;

    // ---- batch A of h-fragments (kt 0..3): issue loads early --------------
    ull_t lo[4], hi[4];
    #pragma unroll
    for (int kt = 0; kt < 4; ++kt) {
      const size_t ci = ((size_t)(kc0 + kt * 4) * 64 + hrow) * 2;
      lo[kt] = __hip_atomic_load(hb + ci,     __ATOMIC_RELAXED, __HIP_MEMORY_SCOPE_AGENT);
      hi[kt] = __hip_atomic_load(hb + ci + 1, __ATOMIC_RELAXED, __HIP_MEMORY_SCOPE_AGENT);
    }

    f32x4 acc = {0.f, 0.f, 0.f, 0.f};
    { // ---- x-pass: 4 MFMA from LDS (overlaps batch-A load latency) --------
      #pragma unroll
      for (int kt = 0; kt < 4; ++kt) {
        const int col = kg * 256 + kt * 64 + lkb;
        union { uint4 u; half8 hv; } U;
        U.u = *(const uint4*)(xbase + (col ^ akey));
        acc = __builtin_amdgcn_mfma_f32_16x16x32_f16(U.hv, wx[kt], acc, 0, 0, 0);
      }
    }

    // ---- batch B of h-fragments (kt 4..7): issue, then consume A ---------
    ull_t lo2[4], hi2[4];
    #pragma unroll
    for (int kt = 0; kt < 4; ++kt) {
      const size_t ci = ((size_t)(kc0 + (kt + 4) * 4) * 64 + hrow) * 2;
      lo2[kt] = __hip_atomic_load(hb + ci,     __ATOMIC_RELAXED, __HIP_MEMORY_SCOPE_AGENT);
      hi2[kt] = __hip_atomic_load(hb + ci + 1, __ATOMIC_RELAXED, __HIP_MEMORY_SCOPE_AGENT);
    }
    #pragma unroll
    for (int kt = 0; kt < 4; ++kt) {
      union { ull_t u[2]; half8 hv; } U;
      U.u[0] = lo[kt]; U.u[1] = hi[kt];
      acc = __builtin_amdgcn_mfma_f32_16x16x32_f16(U.hv, wh[kt], acc, 0, 0, 0);
    }
    #pragma unroll
    for (int kt = 0; kt < 4; ++kt) {
      union { ull_t u[2]; half8 hv; } U;
      U.u[0] = lo2[kt]; U.u[1] = hi2[kt];
      acc = __builtin_amdgcn_mfma_f32_16x16x32_f16(U.hv, wh[kt + 4], acc, 0, 0, 0);
    }

    // ---- partials (D layout: col=lane&15, row=(lane>>4)*4+r) -------------
    #pragma unroll
    for (int r = 0; r < 4; ++r)
      part[kg][bt * 16 + (lane >> 4) * 4 + r][lr] = acc[r];
    __syncthreads();

    if (tid < 256) {  // ---- combine (fixed order, identical r12) ----------
      float s0 = 0.f, s1 = 0.f, s2 = 0.f, s3 = 0.f;
      #pragma unroll
      for (int k2 = 0; k2 < 4; ++k2) {
        s0 += part[k2][cb][jj];
        s1 += part[k2][cb][4 + jj];
        s2 += part[k2][cb][8 + jj];
        s3 += part[k2][cb][12 + jj];
      }
      m0 += s0; m1 += s1; m2 += s2; m3 += s3;

      float pi = qA(m0), pf = qA(m1), pg = qA(m2), po = qA(m3);
      float gi = qN(sigm(pi));
      float gf = qN(sigm(pf));
      float gg = qN(tanhf(pg));
      float go = qN(sigm(po));
      float cn = c * gf + gi * gg;
      c = qA(cn);
      float ct = qN(tanhf(c));
      h = qA(go * ct);
      out[(size_t)t * (BATCH * HSZ) + (size_t)cb * HSZ + j] = h;

      if (t < TSTEPS - 1) {
        float d  = h - hp;
        float da = fabsf(d);
        float dm = (da < TH_QNT) ? 0.0f : d;
        if (da >= TH_RAW) hp = h;
        regacc += fabsf(dm);
        // pack 4 halves (jj=0..3 of this cb) into one u64, store to frag cell
        ushort_t my = __half_as_ushort(__float2half(dm));   // fp16 exact for dh
        int v1 = __shfl((int)my, lane + 1, 64);
        int v2 = __shfl((int)my, lane + 2, 64);
        int v3 = __shfl((int)my, lane + 3, 64);
        if (jj == 0) {
          ull_t dw = (ull_t)my | ((ull_t)(ushort_t)v1 << 16) |
                     ((ull_t)(ushort_t)v2 << 32) | ((ull_t)(ushort_t)v3 << 48);
          ull_t* dhw = (ull_t*)(dh16 + (size_t)((t + 1) & 1) * DHFRAG);
          __hip_atomic_store(dhw + dhcell2, dw,
                             __ATOMIC_RELAXED, __HIP_MEMORY_SCOPE_AGENT);
        }
      }
    }

    gbar_arrive(flags, epoch);

    if (t < TSTEPS - 1) {  // ---- stage dx[t+1] in the barrier-wait shadow --
      const ull_t* __restrict__ sx =
          (const ull_t*)(dx16 + (size_t)(t + 1) * (BATCH * ISZ));
      unsigned char* dst = &dxbuf[(t + 1) & 1][0];
      #pragma unroll
      for (int i = 0; i < 8; ++i) {
        ull_t v = sx[i * 1024 + tid];
        const int u = i * 1024 + tid;
        const int row = u >> 7, cc = u & 127;
        *(ull_t*)(dst + row * 1024 + ((cc * 8) ^ ((row & 7) << 4))) = v;
      }
    }

    gbar_wait(flags, epoch);
    epoch++;
  }

  if (tid < 256) {  // final state dump
    out[OFF_H  + (size_t)cb * HSZ + j] = h;
    out[OFF_HP + (size_t)cb * HSZ + j] = hp;
    out[OFF_C  + (size_t)cb * HSZ + j] = c;
    out[OFF_M  + (size_t)cb * GSZ + g0] = m0;
    out[OFF_M  + (size_t)cb * GSZ + g1] = m1;
    out[OFF_M  + (size_t)cb * GSZ + g2] = m2;
    out[OFF_M  + (size_t)cb * GSZ + g3] = m3;
  }

  // deterministic reg reduction
  if (tid < 256) red[tid] = regacc;
  __syncthreads();
  for (int s = 128; s > 0; s >>= 1) {
    if (tid < s) red[tid] += red[tid + s];
    __syncthreads();
  }
  if (tid == 0)
    __hip_atomic_store(&partials[blockIdx.x], red[0], __ATOMIC_RELAXED, __HIP_MEMORY_SCOPE_AGENT);
  gbar_arrive(flags, epoch);
  gbar_wait(flags, epoch);
  epoch++;
  if (blockIdx.x == 0) {
    if (tid < 256)
      red[tid] = __hip_atomic_load(&partials[tid], __ATOMIC_RELAXED, __HIP_MEMORY_SCOPE_AGENT);
    __syncthreads();
    for (int s = 128; s > 0; s >>= 1) {
      if (tid < s) red[tid] += red[tid + s];
      __syncthreads();
    }
    if (tid == 0) out[OFF_REG] = red[0];
  }
}

// ---------------------------------------------------------------------------
extern "C" void kernel_launch(void* const* d_in, const int* in_sizes, int n_in,
                              void* d_out, int out_size, void* d_ws, size_t ws_size,
                              hipStream_t stream) {
  const float* x    = (const float*)d_in[0];
  const float* w_ih = (const float*)d_in[1];
  const float* w_hh = (const float*)d_in[2];
  const float* b_ih = (const float*)d_in[3];
  const float* b_hh = (const float*)d_in[4];
  float* out = (float*)d_out;

  const size_t dx_elems = (size_t)TSTEPS * BATCH * ISZ;   // fp16: 33.5 MB
  __half* dx16     = (__half*)d_ws;
  __half* dh16     = dx16 + dx_elems;                     // 2 x DHFRAG halves
  float*  partials = (float*)(dh16 + 2 * (size_t)DHFRAG);
  int*    flags    = (int*)(partials + NB);
  size_t needed = (size_t)((char*)(flags + NB) - (char*)d_ws);
  if (ws_size < needed) return;

  (void)hipMemsetAsync(dh16, 0, 2 * (size_t)DHFRAG * sizeof(__half), stream);
  (void)hipMemsetAsync(flags, 0, NB * sizeof(int), stream);
  xscan_kernel<<<128, 256, 0, stream>>>(x, dx16, out + OFF_XPREV);
  scan_kernel<<<NB, NTH, 0, stream>>>(dx16, w_ih, w_hh, b_ih, b_hh, out,
                                      dh16, partials, flags);
}